// Round 3
// baseline (174.206 us; speedup 1.0000x reference)
//
#include <hip/hip_runtime.h>
#include <math.h>

#define B 512
#define M 4096
#define T 48
#define MCHUNK 8
#define NCH (M / MCHUNK)   // 512 m-chunks

// ws layout (bytes):
//   [0, 512*512*8) pval[b][ch]: packed (float_bits(dist)<<32 | m), u64

// ---------------- Kernel 1: lane-per-b distance, packed per-chunk min -------
// lane = one batch row b (target row held in 96 registers);
// memory row address is wave-uniform -> scalar loads (SGPRs, no VGPR cost).
__global__ __launch_bounds__(256, 4) void k_dist(const float* __restrict__ target,
                                                 const float* __restrict__ memory,
                                                 unsigned long long* __restrict__ pval,
                                                 float* __restrict__ out0) {
    const int tid = threadIdx.x;
    const int b   = blockIdx.y * 256 + tid;
    const int ch  = blockIdx.x;
    const int m0  = ch * MCHUNK;

    // zero the loss accumulator (k_post runs after k_dist in stream order)
    if (ch == 0 && blockIdx.y == 0 && tid == 0) out0[0] = 0.0f;

    // Per-lane target row -> registers (static indices only)
    float gt[T * 2];
    const float4* tg = (const float4*)(target + (size_t)b * (T * 2));
#pragma unroll
    for (int q = 0; q < T / 2; ++q) {
        float4 v = tg[q];
        gt[4 * q + 0] = v.x; gt[4 * q + 1] = v.y;
        gt[4 * q + 2] = v.z; gt[4 * q + 3] = v.w;
    }

    float bestv = INFINITY;
    int   besti = 0;

#pragma unroll
    for (int mi = 0; mi < MCHUNK; ++mi) {
        const int m = m0 + mi;                       // wave-uniform
        const float4* mr = (const float4*)(memory + (size_t)m * (T * 2));
        float a0 = 0.f, a1 = 0.f, a2 = 0.f, a3 = 0.f;
#pragma unroll
        for (int q = 0; q < T / 2; ++q) {
            float4 mv = mr[q];                       // uniform addr -> s_load
            float dx0 = mv.x - gt[4 * q + 0];
            float dy0 = mv.y - gt[4 * q + 1];
            float dx1 = mv.z - gt[4 * q + 2];
            float dy1 = mv.w - gt[4 * q + 3];
            float s0 = __builtin_amdgcn_sqrtf(fmaf(dx0, dx0, dy0 * dy0));
            float s1 = __builtin_amdgcn_sqrtf(fmaf(dx1, dx1, dy1 * dy1));
            if (q & 1) { a2 += s0; a3 += s1; }
            else       { a0 += s0; a1 += s1; }
        }
        float d = (a0 + a2) + (a1 + a3);
        if (d < bestv) { bestv = d; besti = m; }     // ascending m -> lowest idx on tie
    }

    // positive float bits compare like uint; low word = index -> lowest index wins ties
    pval[(size_t)b * NCH + ch] =
        ((unsigned long long)__float_as_uint(bestv) << 32) | (unsigned int)besti;
}

// ---------------- Kernel 2: argmin across chunks + LSE + NLL + mean ---------
__global__ __launch_bounds__(256) void k_post(const float* __restrict__ preds,
                                              const unsigned long long* __restrict__ pval,
                                              float* __restrict__ out) {
    const int b   = blockIdx.x;
    const int tid = threadIdx.x;

    __shared__ unsigned long long sm[256];
    __shared__ float red[256];

    // --- argmin over 512 chunks (u64 min == lexicographic (dist, idx) min) ---
    unsigned long long p0 = pval[(size_t)b * NCH + tid];
    unsigned long long p1 = pval[(size_t)b * NCH + 256 + tid];
    sm[tid] = p0 < p1 ? p0 : p1;
    __syncthreads();
    for (int s = 128; s > 0; s >>= 1) {
        if (tid < s) { unsigned long long o = sm[tid + s]; if (o < sm[tid]) sm[tid] = o; }
        __syncthreads();
    }
    const int idx = (int)(unsigned int)(sm[0] & 0xFFFFFFFFULL);
    __syncthreads();

    // --- LSE over preds row ---
    const float4* row = (const float4*)(preds + (size_t)b * M);  // 1024 float4
    float4 v[4];
    float mx = -INFINITY;
#pragma unroll
    for (int j = 0; j < 4; ++j) {
        v[j] = row[tid + j * 256];
        mx = fmaxf(mx, fmaxf(fmaxf(v[j].x, v[j].y), fmaxf(v[j].z, v[j].w)));
    }
    red[tid] = mx; __syncthreads();
    for (int s = 128; s > 0; s >>= 1) {
        if (tid < s) red[tid] = fmaxf(red[tid], red[tid + s]);
        __syncthreads();
    }
    mx = red[0];
    __syncthreads();

    float sum = 0.f;
#pragma unroll
    for (int j = 0; j < 4; ++j)
        sum += expf(v[j].x - mx) + expf(v[j].y - mx) + expf(v[j].z - mx) + expf(v[j].w - mx);
    red[tid] = sum; __syncthreads();
    for (int s = 128; s > 0; s >>= 1) {
        if (tid < s) red[tid] += red[tid + s];
        __syncthreads();
    }

    if (tid == 0) {
        float lse = mx + logf(red[0]);
        float nll = lse - preds[(size_t)b * M + idx];
        atomicAdd(out, nll * (1.0f / B));   // out[0] zeroed by k_dist
        out[1 + b] = (float)idx;
    }
}

extern "C" void kernel_launch(void* const* d_in, const int* in_sizes, int n_in,
                              void* d_out, int out_size, void* d_ws, size_t ws_size,
                              hipStream_t stream) {
    const float* preds  = (const float*)d_in[0];  // (512, 4096)
    const float* target = (const float*)d_in[1];  // (512, 1, 48, 2)
    const float* memory = (const float*)d_in[2];  // (4096, 48, 2)
    float* out = (float*)d_out;                   // [loss, idx[512]]

    unsigned long long* pval = (unsigned long long*)d_ws;  // 512*512 u64 = 2 MB

    dim3 g1(NCH, B / 256);                        // 512 x 2 = 1024 blocks
    k_dist<<<g1, 256, 0, stream>>>(target, memory, pval, out);
    k_post<<<B, 256, 0, stream>>>(preds, pval, out);
}

// Round 4
// 44.273 us; speedup vs baseline: 3.9348x; 3.9348x over previous
//
#include <hip/hip_runtime.h>
#include <math.h>

#define B 512
#define M 4096
#define T 48
#define MCHUNK 8
#define NCH (M / MCHUNK)   // 512 m-chunks

// ws layout (bytes):
//   [0, 2 MiB)            pval[b][ch]: packed (float_bits(dist)<<32 | m), u64
//   [2 MiB, 2 MiB+192KiB) tgtT[t][b] float2 (transposed target)

// ------------- Kernel 0: transpose target (B,T,2) -> (T,B,2) ---------------
__global__ __launch_bounds__(256) void k_transpose(const float* __restrict__ target,
                                                   float2* __restrict__ tgtT) {
    int i = blockIdx.x * 256 + threadIdx.x;    // over B*T float2, b-major
    int b = i / T, t = i - b * T;
    float2 v = ((const float2*)target)[i];     // coalesced read
    tgtT[t * B + b] = v;                       // scattered 8B write (196 KB total)
}

// ------------- Kernel 1: q-outer / m-inner distance, acc-per-m -------------
// lane = batch row b; target read coalesced from tgtT; memory rows are
// wave-uniform -> scalar loads. Per-lane state: acc[8] + 2 float2 => ~30 VGPR.
__global__ __launch_bounds__(256, 4) void k_dist(const float2* __restrict__ tgtT,
                                                 const float* __restrict__ memory,
                                                 unsigned long long* __restrict__ pval,
                                                 float* __restrict__ out0) {
    const int tid = threadIdx.x;
    const int b   = blockIdx.y * 256 + tid;
    const int ch  = blockIdx.x;
    const int m0  = ch * MCHUNK;

    // zero the loss accumulator (k_post runs after in stream order)
    if (ch == 0 && blockIdx.y == 0 && tid == 0) out0[0] = 0.0f;

    float acc[MCHUNK];
#pragma unroll
    for (int i = 0; i < MCHUNK; ++i) acc[i] = 0.f;

    for (int q = 0; q < T / 2; ++q) {          // t = 2q, 2q+1
        float2 g0 = tgtT[(2 * q)     * B + b]; // coalesced
        float2 g1 = tgtT[(2 * q + 1) * B + b];
#pragma unroll
        for (int mi = 0; mi < MCHUNK; ++mi) {
            const float4* mr = (const float4*)(memory + (size_t)(m0 + mi) * (T * 2));
            float4 mv = mr[q];                 // wave-uniform -> s_load
            float dx0 = mv.x - g0.x, dy0 = mv.y - g0.y;
            float dx1 = mv.z - g1.x, dy1 = mv.w - g1.y;
            acc[mi] += __builtin_amdgcn_sqrtf(fmaf(dx0, dx0, dy0 * dy0));
            acc[mi] += __builtin_amdgcn_sqrtf(fmaf(dx1, dx1, dy1 * dy1));
        }
    }

    float bestv = INFINITY;
    int   besti = 0;
#pragma unroll
    for (int mi = 0; mi < MCHUNK; ++mi)        // ascending m -> lowest idx on tie
        if (acc[mi] < bestv) { bestv = acc[mi]; besti = m0 + mi; }

    // positive float bits compare like uint; low word = index -> lowest index wins ties
    pval[(size_t)b * NCH + ch] =
        ((unsigned long long)__float_as_uint(bestv) << 32) | (unsigned int)besti;
}

// ---------------- Kernel 2: argmin across chunks + LSE + NLL + mean ---------
__global__ __launch_bounds__(256) void k_post(const float* __restrict__ preds,
                                              const unsigned long long* __restrict__ pval,
                                              float* __restrict__ out) {
    const int b   = blockIdx.x;
    const int tid = threadIdx.x;

    __shared__ unsigned long long sm[256];
    __shared__ float red[256];

    // --- argmin over 512 chunks (u64 min == lexicographic (dist, idx) min) ---
    unsigned long long p0 = pval[(size_t)b * NCH + tid];
    unsigned long long p1 = pval[(size_t)b * NCH + 256 + tid];
    sm[tid] = p0 < p1 ? p0 : p1;
    __syncthreads();
    for (int s = 128; s > 0; s >>= 1) {
        if (tid < s) { unsigned long long o = sm[tid + s]; if (o < sm[tid]) sm[tid] = o; }
        __syncthreads();
    }
    const int idx = (int)(unsigned int)(sm[0] & 0xFFFFFFFFULL);
    __syncthreads();

    // --- LSE over preds row ---
    const float4* row = (const float4*)(preds + (size_t)b * M);  // 1024 float4
    float4 v[4];
    float mx = -INFINITY;
#pragma unroll
    for (int j = 0; j < 4; ++j) {
        v[j] = row[tid + j * 256];
        mx = fmaxf(mx, fmaxf(fmaxf(v[j].x, v[j].y), fmaxf(v[j].z, v[j].w)));
    }
    red[tid] = mx; __syncthreads();
    for (int s = 128; s > 0; s >>= 1) {
        if (tid < s) red[tid] = fmaxf(red[tid], red[tid + s]);
        __syncthreads();
    }
    mx = red[0];
    __syncthreads();

    float sum = 0.f;
#pragma unroll
    for (int j = 0; j < 4; ++j)
        sum += expf(v[j].x - mx) + expf(v[j].y - mx) + expf(v[j].z - mx) + expf(v[j].w - mx);
    red[tid] = sum; __syncthreads();
    for (int s = 128; s > 0; s >>= 1) {
        if (tid < s) red[tid] += red[tid + s];
        __syncthreads();
    }

    if (tid == 0) {
        float lse = mx + logf(red[0]);
        float nll = lse - preds[(size_t)b * M + idx];
        atomicAdd(out, nll * (1.0f / B));   // out[0] zeroed by k_dist
        out[1 + b] = (float)idx;
    }
}

extern "C" void kernel_launch(void* const* d_in, const int* in_sizes, int n_in,
                              void* d_out, int out_size, void* d_ws, size_t ws_size,
                              hipStream_t stream) {
    const float* preds  = (const float*)d_in[0];  // (512, 4096)
    const float* target = (const float*)d_in[1];  // (512, 1, 48, 2)
    const float* memory = (const float*)d_in[2];  // (4096, 48, 2)
    float* out = (float*)d_out;                   // [loss, idx[512]]

    char* ws = (char*)d_ws;
    unsigned long long* pval = (unsigned long long*)ws;        // 512*512 u64 = 2 MiB
    float2* tgtT = (float2*)(ws + (size_t)2 * 1024 * 1024);    // 48*512 float2 = 192 KiB

    k_transpose<<<(B * T) / 256, 256, 0, stream>>>(target, tgtT);
    dim3 g1(NCH, B / 256);                        // 512 x 2 = 1024 blocks
    k_dist<<<g1, 256, 0, stream>>>(tgtT, memory, pval, out);
    k_post<<<B, 256, 0, stream>>>(preds, pval, out);
}